// Round 1
// baseline (2677.810 us; speedup 1.0000x reference)
//
#include <hip/hip_runtime.h>
#include <stdint.h>

#define T_STEPS 512
#define BATCH   256
#define INP     128
#define HID     512
#define BGN     16   // batch groups
#define CGN     16   // column groups
#define RB      16   // rows per block
#define CB      32   // h-cols per block
#define ZPITCH  648  // LDS z row pitch in u16 (640 + 8 pad)

typedef float f32x4 __attribute__((ext_vector_type(4)));
typedef short s16x8 __attribute__((ext_vector_type(8)));
typedef unsigned short u16;
typedef unsigned long long u64;

__device__ __forceinline__ u16 f2bf(float f) {
  union { float f; unsigned u; } v; v.f = f;
  unsigned r = v.u + 0x7fffu + ((v.u >> 16) & 1u);  // round-to-nearest-even
  return (u16)(r >> 16);
}

// hb layout: [2][BATCH][HID] bf16 bits (double buffer), then flags.
// flags: [BGN][CGN] ints, each padded to 64B (stride 16 ints).
// flag value t+1 means block (bg,cg) completed step t (incl. its h reads).

__global__ __launch_bounds__(256, 1)
void liquid_persistent(const float* __restrict__ x_seq,
                       const float* __restrict__ Wc, const float* __restrict__ bc,
                       const float* __restrict__ Wt, const float* __restrict__ bt,
                       const float* __restrict__ Wo, const float* __restrict__ bo,
                       float* __restrict__ y_out, float* __restrict__ tau_out,
                       u16* __restrict__ hb, int* __restrict__ flags)
{
  const int tid  = threadIdx.x;
  const int l    = tid & 63;
  const int w    = tid >> 6;        // wave 0..3
  const int quad = l >> 4;
  const int ln   = l & 15;
  const int bg   = blockIdx.x & (BGN - 1);
  const int cg   = blockIdx.x >> 4;
  const int R0   = bg * RB;
  const int C0   = cg * CB;

  __shared__ u16   zS[RB][ZPITCH];        // [x_t ; h_t] bf16, 16 rows x 640
  __shared__ float ctC[CB][RB + 1];       // candidate preact [col][row]
  __shared__ float ctT[CB][RB + 1];       // tau preact

  // ---- preload register-resident B fragments (once) ----
  // waves 0,1 -> Wc cols C0+(w&1)*16+ln ; waves 2,3 -> Wt
  const float* Wm = (w < 2) ? Wc : Wt;
  const int ncol = C0 + (w & 1) * 16 + ln;
  s16x8 wf[20];
#pragma unroll
  for (int kt = 0; kt < 20; ++kt) {
#pragma unroll
    for (int j = 0; j < 8; ++j) {
      int k = kt * 32 + quad * 8 + j;       // B layout: n=lane&15, k=quad*8+j
      wf[kt][j] = (short)f2bf(Wm[k * HID + ncol]);
    }
  }

  // epilogue constants: thread owns (erow, C0+ecol) and (erow, C0+ecol+1)
  const int erow = tid >> 4;
  const int ecol = (tid * 2) & 31;
  const float bc0 = bc[C0 + ecol], bc1 = bc[C0 + ecol + 1];
  const float bt0 = bt[C0 + ecol], bt1 = bt[C0 + ecol + 1];
  const float wo0 = Wo[C0 + ecol], wo1 = Wo[C0 + ecol + 1];
  const float boadd = (cg == 0) ? bo[0] : 0.0f;
  float h0 = 0.0f, h1 = 0.0f;               // fp32 master h state

  const int xrow = tid >> 4;                // staging row 0..15
  const int xseg = tid & 15;
  int* myflags = flags + bg * (CGN * 16);

  for (int t = 0; t < T_STEPS; ++t) {
    const int p = t & 1;

    // ---- wait for all 16 col-groups of this batch-group to finish step t-1 ----
    if (t > 0 && tid < CGN) {
      while (__hip_atomic_load(&myflags[tid * 16], __ATOMIC_RELAXED,
                               __HIP_MEMORY_SCOPE_AGENT) < t) { }
    }
    __syncthreads();

    // ---- stage x_t (fp32 -> bf16) ----
    {
      const float* xp = x_seq + ((size_t)t * BATCH + R0 + xrow) * INP + xseg * 8;
      float4 a = *(const float4*)xp;
      float4 b = *(const float4*)(xp + 4);
      u64 w0 = (u64)f2bf(a.x) | ((u64)f2bf(a.y) << 16) |
               ((u64)f2bf(a.z) << 32) | ((u64)f2bf(a.w) << 48);
      u64 w1 = (u64)f2bf(b.x) | ((u64)f2bf(b.y) << 16) |
               ((u64)f2bf(b.z) << 32) | ((u64)f2bf(b.w) << 48);
      *(u64*)&zS[xrow][xseg * 8]     = w0;
      *(u64*)&zS[xrow][xseg * 8 + 4] = w1;
    }
    // ---- stage h_t from global (agent-scope loads bypass stale L2) ----
    {
      const u64* hrow = (const u64*)hb + ((size_t)p * BATCH + R0 + xrow) * (HID / 4);
#pragma unroll
      for (int i = 0; i < 8; ++i) {
        u64 v = __hip_atomic_load((u64*)&hrow[i * 16 + xseg], __ATOMIC_RELAXED,
                                  __HIP_MEMORY_SCOPE_AGENT);
        *(u64*)&zS[xrow][INP + (i * 16 + xseg) * 4] = v;
      }
    }
    __syncthreads();

    // ---- MFMA: [16 x 640] @ [640 x 16-per-wave], 2 interleaved accumulators ----
    f32x4 acc0 = {0.f, 0.f, 0.f, 0.f};
    f32x4 acc1 = {0.f, 0.f, 0.f, 0.f};
    const u16* zbase = &zS[ln][quad * 8];   // A layout: m=lane&15, k=quad*8+j
#pragma unroll
    for (int kt = 0; kt < 20; kt += 2) {
      s16x8 a0 = *(const s16x8*)(zbase + kt * 32);
      s16x8 a1 = *(const s16x8*)(zbase + kt * 32 + 32);
      acc0 = __builtin_amdgcn_mfma_f32_16x16x32_bf16(a0, wf[kt],     acc0, 0, 0, 0);
      acc1 = __builtin_amdgcn_mfma_f32_16x16x32_bf16(a1, wf[kt + 1], acc1, 0, 0, 0);
    }
    acc0 += acc1;

    // ---- C tiles -> LDS (C/D layout: col=lane&15, row=quad*4+reg) ----
    {
      float (*ct)[RB + 1] = (w < 2) ? ctC : ctT;
      int cb = (w & 1) * 16 + ln;
#pragma unroll
      for (int r = 0; r < 4; ++r) ct[cb][quad * 4 + r] = acc0[r];
    }
    __syncthreads();

    // ---- fused epilogue: activations, Euler update, outputs, h exchange ----
    {
      float pc0 = ctC[ecol][erow]     + bc0;
      float pc1 = ctC[ecol + 1][erow] + bc1;
      float pt0 = ctT[ecol][erow]     + bt0;
      float pt1 = ctT[ecol + 1][erow] + bt1;
      pc0 = fminf(fmaxf(pc0, -20.f), 20.f);
      pc1 = fminf(fmaxf(pc1, -20.f), 20.f);
      float e0 = __expf(2.f * pc0);
      float e1 = __expf(2.f * pc1);
      float cand0 = (e0 - 1.f) / (e0 + 1.f);     // tanh
      float cand1 = (e1 - 1.f) / (e1 + 1.f);
      float tau0 = 0.2f + 1.8f / (1.f + __expf(-pt0));
      float tau1 = 0.2f + 1.8f / (1.f + __expf(-pt1));
      h0 += 0.1f * (cand0 - h0) / tau0;
      h1 += 0.1f * (cand1 - h1) / tau1;

      size_t tix = ((size_t)t * BATCH + R0 + erow) * HID + C0 + ecol;
      float2 tv; tv.x = tau0; tv.y = tau1;
      *(float2*)&tau_out[tix] = tv;

      unsigned pk = (unsigned)f2bf(h0) | ((unsigned)f2bf(h1) << 16);
      unsigned* hp = (unsigned*)hb +
          (((size_t)(p ^ 1) * BATCH + R0 + erow) * HID + C0 + ecol) / 2;
      __hip_atomic_store(hp, pk, __ATOMIC_RELAXED, __HIP_MEMORY_SCOPE_AGENT);

      float py = h0 * wo0 + h1 * wo1;            // partial y over this col slice
      py += __shfl_down(py, 8);
      py += __shfl_down(py, 4);
      py += __shfl_down(py, 2);
      py += __shfl_down(py, 1);
      if ((tid & 15) == 0)
        atomicAdd(&y_out[t * BATCH + R0 + erow], py + boadd);
    }

    // barrier's per-wave s_waitcnt vmcnt(0) drains every wave's h stores
    // before thread 0 publishes the flag -> release not needed on the flag.
    __syncthreads();
    if (tid == 0) {
      __hip_atomic_store(&myflags[cg * 16], t + 1, __ATOMIC_RELAXED,
                         __HIP_MEMORY_SCOPE_AGENT);
    }
  }
}

extern "C" void kernel_launch(void* const* d_in, const int* in_sizes, int n_in,
                              void* d_out, int out_size, void* d_ws, size_t ws_size,
                              hipStream_t stream) {
  (void)in_sizes; (void)n_in; (void)out_size; (void)ws_size;
  const float* x_seq = (const float*)d_in[0];
  const float* Wc    = (const float*)d_in[1];
  const float* bc    = (const float*)d_in[2];
  const float* Wt    = (const float*)d_in[3];
  const float* bt    = (const float*)d_in[4];
  const float* Wo    = (const float*)d_in[5];
  const float* bo    = (const float*)d_in[6];

  float* y_out   = (float*)d_out;                              // [T*B]
  float* tau_out = (float*)d_out + (size_t)T_STEPS * BATCH;    // [T*B*H]

  const size_t HB_BYTES   = (size_t)2 * BATCH * HID * sizeof(u16); // 524288
  const size_t FLAG_BYTES = (size_t)BGN * CGN * 16 * sizeof(int);  // 16384
  u16* hb    = (u16*)d_ws;
  int* flags = (int*)((char*)d_ws + HB_BYTES);

  // y must start at zero (atomicAdd accumulation); h0 = 0; flags = 0.
  hipMemsetAsync(d_out, 0, (size_t)T_STEPS * BATCH * sizeof(float), stream);
  hipMemsetAsync(d_ws, 0, HB_BYTES + FLAG_BYTES, stream);

  liquid_persistent<<<dim3(BGN * CGN), dim3(256), 0, stream>>>(
      x_seq, Wc, bc, Wt, bt, Wo, bo, y_out, tau_out, hb, flags);
}

// Round 2
// 2030.085 us; speedup vs baseline: 1.3191x; 1.3191x over previous
//
#include <hip/hip_runtime.h>
#include <stdint.h>

#define T_STEPS 512
#define BATCH   256
#define INP     128
#define HID     512
#define BGN     16   // batch groups
#define CGN     8    // column groups
#define RB      16   // rows per block
#define CB      64   // h-cols per block (16 per wave, both matrices per wave)
#define ZP      648  // LDS z row pitch in u16 (640 + 8 pad)

typedef float f32x4 __attribute__((ext_vector_type(4)));
typedef short s16x8 __attribute__((ext_vector_type(8)));
typedef unsigned short u16;
typedef unsigned int   u32;
typedef unsigned long long u64;

__device__ __forceinline__ u32 f2bf(float f) {
  union { float f; u32 u; } v; v.f = f;
  return (v.u + 0x7fffu + ((v.u >> 16) & 1u)) >> 16;  // RNE, returns bits in low 16
}

// d_ws layout: hb [2][BATCH][HID] bf16 (double buffer, 512KB), then flags.
// flags[bg][cg] ints padded to 64B (stride 16). flag==t+1 : block (bg,cg)
// finished step t including its h reads (so peers may overwrite buffer t-1).

__global__ __launch_bounds__(256, 1)
void liquid_persistent(const float* __restrict__ x_seq,
                       const float* __restrict__ Wc, const float* __restrict__ bc,
                       const float* __restrict__ Wt, const float* __restrict__ bt,
                       const float* __restrict__ Wo, const float* __restrict__ bo,
                       float* __restrict__ y_out, float* __restrict__ tau_out,
                       u16* __restrict__ hb, int* __restrict__ flags)
{
  const int tid  = threadIdx.x;
  const int l    = tid & 63;
  const int w    = tid >> 6;          // wave 0..3
  const int quad = l >> 4;
  const int ln   = l & 15;
  const int bg   = blockIdx.x & (BGN - 1);
  const int cg   = blockIdx.x >> 4;   // 0..7
  const int R0   = bg * RB;
  const int C0   = cg * CB;
  const int cn   = C0 + w * 16 + ln;  // this lane's output column (both matrices)

  __shared__ u16 zS[RB][ZP];          // [x(128) ; h(512)] bf16 per row

  // ---- register-resident weights: BOTH matrices for this wave's 16 cols ----
  // B layout (m89-verified): n = lane&15, k = quad*8 + j
  s16x8 wfC[20], wfT[20];
#pragma unroll
  for (int kt = 0; kt < 20; ++kt) {
#pragma unroll
    for (int j = 0; j < 8; ++j) {
      int k = kt * 32 + quad * 8 + j;
      wfC[kt][j] = (short)f2bf(Wc[k * HID + cn]);
      wfT[kt][j] = (short)f2bf(Wt[k * HID + cn]);
    }
  }

  const float bcv = bc[cn], btv = bt[cn], wov = Wo[cn];
  const float boadd = (cg == 0 && w == 0) ? bo[0] : 0.0f; // added by ln==0 lanes
  float hm[4] = {0.f, 0.f, 0.f, 0.f};  // fp32 master h: rows quad*4+r, col cn

  const int xrow = tid >> 4;   // staging row 0..15
  const int xseg = tid & 15;
  int* myflags = flags + bg * (CGN * 16);

  // ---- pre-stage x(0) into zS.x ----
  {
    const float* xp = x_seq + ((size_t)0 * BATCH + R0 + xrow) * INP + xseg * 8;
    float4 a = *(const float4*)xp;
    float4 b = *(const float4*)(xp + 4);
    u64 w0 = (u64)f2bf(a.x) | ((u64)f2bf(a.y) << 16) |
             ((u64)f2bf(a.z) << 32) | ((u64)f2bf(a.w) << 48);
    u64 w1 = (u64)f2bf(b.x) | ((u64)f2bf(b.y) << 16) |
             ((u64)f2bf(b.z) << 32) | ((u64)f2bf(b.w) << 48);
    *(u64*)&zS[xrow][xseg * 8]     = w0;
    *(u64*)&zS[xrow][xseg * 8 + 4] = w1;
  }
  __syncthreads();

  for (int t = 0; t < T_STEPS; ++t) {
    const int p = t & 1;

    // ---- Phase A: x-part MFMAs (independent of h exchange) ----
    f32x4 aC0 = {0.f,0.f,0.f,0.f}, aC1 = {0.f,0.f,0.f,0.f};
    f32x4 aT0 = {0.f,0.f,0.f,0.f}, aT1 = {0.f,0.f,0.f,0.f};
    const u16* zb = &zS[ln][quad * 8];   // A layout: m=lane&15, k=quad*8+j
    {
      s16x8 a0 = *(const s16x8*)(zb);
      s16x8 a1 = *(const s16x8*)(zb + 32);
      s16x8 a2 = *(const s16x8*)(zb + 64);
      s16x8 a3 = *(const s16x8*)(zb + 96);
      aC0 = __builtin_amdgcn_mfma_f32_16x16x32_bf16(a0, wfC[0], aC0, 0,0,0);
      aT0 = __builtin_amdgcn_mfma_f32_16x16x32_bf16(a0, wfT[0], aT0, 0,0,0);
      aC1 = __builtin_amdgcn_mfma_f32_16x16x32_bf16(a1, wfC[1], aC1, 0,0,0);
      aT1 = __builtin_amdgcn_mfma_f32_16x16x32_bf16(a1, wfT[1], aT1, 0,0,0);
      aC0 = __builtin_amdgcn_mfma_f32_16x16x32_bf16(a2, wfC[2], aC0, 0,0,0);
      aT0 = __builtin_amdgcn_mfma_f32_16x16x32_bf16(a2, wfT[2], aT0, 0,0,0);
      aC1 = __builtin_amdgcn_mfma_f32_16x16x32_bf16(a3, wfC[3], aC1, 0,0,0);
      aT1 = __builtin_amdgcn_mfma_f32_16x16x32_bf16(a3, wfT[3], aT1, 0,0,0);
    }

    // ---- x(t+1) prefetch: issue BEFORE the wait (latency hidden by spin) ----
    const int tn = (t + 1 < T_STEPS) ? t + 1 : t;
    const float* xp = x_seq + ((size_t)tn * BATCH + R0 + xrow) * INP + xseg * 8;
    float4 xr0 = *(const float4*)xp;
    float4 xr1 = *(const float4*)(xp + 4);

    // ---- Phase B: wait for peers, gather h ----
    if (t > 0 && tid < CGN) {
      while (__hip_atomic_load(&myflags[tid * 16], __ATOMIC_RELAXED,
                               __HIP_MEMORY_SCOPE_AGENT) < t) { }
    }
    __syncthreads();

    {
      // ALL loads to regs first (one latency), then all LDS writes.
      u64 hv[8];
      u64* hrow = (u64*)hb + ((size_t)p * BATCH + R0 + xrow) * (HID / 4);
#pragma unroll
      for (int i = 0; i < 8; ++i)
        hv[i] = __hip_atomic_load(&hrow[i * 16 + xseg], __ATOMIC_RELAXED,
                                  __HIP_MEMORY_SCOPE_AGENT);
#pragma unroll
      for (int i = 0; i < 8; ++i)
        *(u64*)&zS[xrow][INP + (i * 16 + xseg) * 4] = hv[i];
    }
    __syncthreads();

    // ---- Phase C: h-part MFMAs (4 independent accumulator chains) ----
#pragma unroll
    for (int kt = 4; kt < 20; kt += 2) {
      s16x8 a0 = *(const s16x8*)(zb + kt * 32);
      s16x8 a1 = *(const s16x8*)(zb + kt * 32 + 32);
      aC0 = __builtin_amdgcn_mfma_f32_16x16x32_bf16(a0, wfC[kt],   aC0, 0,0,0);
      aT0 = __builtin_amdgcn_mfma_f32_16x16x32_bf16(a0, wfT[kt],   aT0, 0,0,0);
      aC1 = __builtin_amdgcn_mfma_f32_16x16x32_bf16(a1, wfC[kt+1], aC1, 0,0,0);
      aT1 = __builtin_amdgcn_mfma_f32_16x16x32_bf16(a1, wfT[kt+1], aT1, 0,0,0);
    }
    aC0 += aC1;
    aT0 += aT1;

    // ---- stage x(t+1) into zS.x (safe: all waves past Phase A via barrier) ----
    {
      u64 w0 = (u64)f2bf(xr0.x) | ((u64)f2bf(xr0.y) << 16) |
               ((u64)f2bf(xr0.z) << 32) | ((u64)f2bf(xr0.w) << 48);
      u64 w1 = (u64)f2bf(xr1.x) | ((u64)f2bf(xr1.y) << 16) |
               ((u64)f2bf(xr1.z) << 32) | ((u64)f2bf(xr1.w) << 48);
      *(u64*)&zS[xrow][xseg * 8]     = w0;
      *(u64*)&zS[xrow][xseg * 8 + 4] = w1;
    }

    // ---- Phase D: wave-local epilogue on C-layout (col=ln, row=quad*4+r) ----
    float tauv[4];
#pragma unroll
    for (int r = 0; r < 4; ++r) {
      float pc = aC0[r] + bcv;
      float pt = aT0[r] + btv;
      pc = fminf(fmaxf(pc, -20.f), 20.f);
      float e  = __expf(2.f * pc);
      float cand = (e - 1.f) / (e + 1.f);          // tanh
      float tau  = 0.2f + 1.8f / (1.f + __expf(-pt));
      hm[r] += 0.1f * (cand - hm[r]) / tau;
      tauv[r] = tau;
    }
#pragma unroll
    for (int r = 0; r < 4; ++r) {
      tau_out[((size_t)t * BATCH + R0 + quad * 4 + r) * HID + cn] = tauv[r];
    }

    // h exchange store: pack lane-pairs (cols cn, cn+1) into u32, even lanes store
#pragma unroll
    for (int r = 0; r < 4; ++r) {
      u32 bits = f2bf(hm[r]);
      u32 ob   = (u32)__shfl_xor((int)bits, 1);    // partner col's bf16 bits
      if (!(ln & 1)) {
        u32 pk = bits | (ob << 16);
        u32* hp = (u32*)hb +
            (((size_t)(p ^ 1) * BATCH + R0 + quad * 4 + r) * HID + cn) / 2;
        __hip_atomic_store(hp, pk, __ATOMIC_RELAXED, __HIP_MEMORY_SCOPE_AGENT);
      }
    }

    // y partials: reduce over this wave's 16 cols (within-quad shfl, width 16)
#pragma unroll
    for (int r = 0; r < 4; ++r) {
      float py = hm[r] * wov;
      py += __shfl_down(py, 8, 16);
      py += __shfl_down(py, 4, 16);
      py += __shfl_down(py, 2, 16);
      py += __shfl_down(py, 1, 16);
      if (ln == 0)
        atomicAdd(&y_out[t * BATCH + R0 + quad * 4 + r], py + boadd);
    }

    // barrier drains all waves' h stores (vmcnt(0) before s_barrier) -> then flag
    __syncthreads();
    if (tid == 0) {
      __hip_atomic_store(&myflags[cg * 16], t + 1, __ATOMIC_RELAXED,
                         __HIP_MEMORY_SCOPE_AGENT);
    }
  }
}

extern "C" void kernel_launch(void* const* d_in, const int* in_sizes, int n_in,
                              void* d_out, int out_size, void* d_ws, size_t ws_size,
                              hipStream_t stream) {
  (void)in_sizes; (void)n_in; (void)out_size; (void)ws_size;
  const float* x_seq = (const float*)d_in[0];
  const float* Wc    = (const float*)d_in[1];
  const float* bc    = (const float*)d_in[2];
  const float* Wt    = (const float*)d_in[3];
  const float* bt    = (const float*)d_in[4];
  const float* Wo    = (const float*)d_in[5];
  const float* bo    = (const float*)d_in[6];

  float* y_out   = (float*)d_out;                              // [T*B]
  float* tau_out = (float*)d_out + (size_t)T_STEPS * BATCH;    // [T*B*H]

  const size_t HB_BYTES   = (size_t)2 * BATCH * HID * sizeof(u16); // 524288
  const size_t FLAG_BYTES = (size_t)BGN * CGN * 16 * sizeof(int);  // 8192
  u16* hb    = (u16*)d_ws;
  int* flags = (int*)((char*)d_ws + HB_BYTES);

  hipMemsetAsync(d_out, 0, (size_t)T_STEPS * BATCH * sizeof(float), stream);
  hipMemsetAsync(d_ws, 0, HB_BYTES + FLAG_BYTES, stream);

  liquid_persistent<<<dim3(BGN * CGN), dim3(256), 0, stream>>>(
      x_seq, Wc, bc, Wt, bt, Wo, bo, y_out, tau_out, hb, flags);
}